// Round 19
// baseline (398.675 us; speedup 1.0000x reference)
//
#include <hip/hip_runtime.h>
#include <cstdint>
#include <cstddef>

typedef __attribute__((ext_vector_type(8))) short short8;
typedef __attribute__((ext_vector_type(4))) float f32x4;
typedef __attribute__((ext_vector_type(16))) float f32x16;

#define DEVI static __device__ __forceinline__

DEVI float bf2f(unsigned short b) {
  union { unsigned int u; float f; } v; v.u = ((unsigned int)b) << 16; return v.f;
}
DEVI unsigned short f2bf(float f) {
  union { float f; unsigned int u; } v; v.f = f;
  unsigned int r = v.u + 0x7fffu + ((v.u >> 16) & 1u);   // RTNE
  return (unsigned short)(r >> 16);
}
// pack two positive floats to bf16x2, round-half-up
DEVI unsigned int pk2(float a, float b) {
  union { float f; unsigned int u; } ua, ub; ua.f = a; ub.f = b;
  return ((ua.u + 0x8000u) >> 16) | ((ub.u + 0x8000u) & 0xffff0000u);
}

DEVI void gload16(const void* g, void* l) {
  __builtin_amdgcn_global_load_lds(
      (const __attribute__((address_space(1))) void*)g,
      (__attribute__((address_space(3))) void*)l, 16, 0, 0);
}

DEVI void drain_ldsdma() {
  asm volatile("s_waitcnt vmcnt(0)" ::: "memory");
  __builtin_amdgcn_sched_barrier(0);
}

// ---------------------------------------------------------------------------
// transpose + convert body: in f32 [Kd][Nd] -> out bf16 [Nd][Kd], 64x64 tile
// ---------------------------------------------------------------------------
DEVI void tr_body(const float* in, unsigned short* out, int Kd, int Nd,
                  int n0, int k0, unsigned short (*tile)[72], int t)
{
  int r = t >> 2, cg = (t & 3) * 16;
  const float* src = in + (size_t)(k0 + r) * Nd + n0 + cg;
#pragma unroll
  for (int q = 0; q < 16; q += 4) {
    float4 f = *(const float4*)(src + q);
    ushort4 u;
    u.x = f2bf(f.x); u.y = f2bf(f.y); u.z = f2bf(f.z); u.w = f2bf(f.w);
    *(ushort4*)&tile[r][cg + q] = u;
  }
  __syncthreads();
  unsigned int p[8];
#pragma unroll
  for (int q = 0; q < 8; ++q)
    p[q] = (unsigned int)tile[cg + 2*q][r] | ((unsigned int)tile[cg + 2*q + 1][r] << 16);
  unsigned short* dst = out + (size_t)(n0 + r) * Kd + k0 + cg;
  *(uint4*)dst       = make_uint4(p[0], p[1], p[2], p[3]);
  *(uint4*)(dst + 8) = make_uint4(p[4], p[5], p[6], p[7]);
}

// ---------------------------------------------------------------------------
// merged preprocessing:
//   [0,2048)       f32->bf16 converts (grid-stride)
//   [2048,12416)   w_qkv / w_add_qkv transpose
// ---------------------------------------------------------------------------
__global__ __launch_bounds__(256) void prep(
    const float* __restrict__ spatial, unsigned short* __restrict__ spat_bf,
    const float* __restrict__ prompt,  unsigned short* __restrict__ prom_bf,
    const float* __restrict__ w_qkv,   const float* __restrict__ w_add_qkv,
    unsigned short* __restrict__ wTq,  unsigned short* __restrict__ wTaq)
{
  __shared__ unsigned short tile[64][72];
  const int b = blockIdx.x;
  if (b < 2048) {
    const int n4a = 2048 * 3072 / 4, n4b = 256 * 1536 / 4;
    int i = b * 256 + threadIdx.x;
    int stride = 2048 * 256;
    int total = n4a + n4b;
    for (; i < total; i += stride) {
      const float4* src = (i < n4a) ? &((const float4*)spatial)[i]
                                    : &((const float4*)prompt)[i - n4a];
      ushort4* dst = (i < n4a) ? &((ushort4*)spat_bf)[i] : &((ushort4*)prom_bf)[i - n4a];
      float4 f = *src;
      ushort4 u;
      u.x = f2bf(f.x); u.y = f2bf(f.y); u.z = f2bf(f.z); u.w = f2bf(f.w);
      *dst = u;
    }
  } else {
    int bb = b - 2048;
    int bx = bb % 144, y = bb / 144;
    const float* in;  unsigned short* out;  int Kd, k0;
    if (y < 48) { in = w_qkv;     out = wTq;  Kd = 3072; k0 = y * 64; }
    else        { in = w_add_qkv; out = wTaq; Kd = 1536; k0 = (y - 48) * 64; }
    tr_body(in, out, Kd, 9216, bx * 64, k0, tile, threadIdx.x);
  }
}

// ---------------------------------------------------------------------------
// merged post-GEMM transposes, launched AFTER fuse_rms_rope:
//   [0,1728)     Vf [h][s][e] -> Vt [h][e][s]   (qkv_s region dead)
//   [1728,6336)  w_out / w_add_out f32 -> bf16 transpose (wTq region dead)
// ---------------------------------------------------------------------------
__global__ __launch_bounds__(256) void posttrans(
    const unsigned short* __restrict__ Vf, unsigned short* __restrict__ Vt,
    const float* __restrict__ w_out, const float* __restrict__ w_add_out,
    unsigned short* __restrict__ wTo, unsigned short* __restrict__ wTao)
{
  __shared__ unsigned short tile[64][72];
  const int b = blockIdx.x;
  if (b < 1728) {
    // bf16 per-head transpose: rows=2304, cols=128
    int bx = b & 1, by = (b >> 1) % 36, h = b / 72;
    size_t hoff = (size_t)h * 2304 * 128;
    int e0 = bx * 64, s0 = by * 64;
    int t = threadIdx.x;
    int r = t >> 2, cg = (t & 3) * 16;
    const unsigned short* src = Vf + hoff + (size_t)(s0 + r) * 128 + e0 + cg;
    *(uint4*)&tile[r][cg]     = *(const uint4*)src;
    *(uint4*)&tile[r][cg + 8] = *(const uint4*)(src + 8);
    __syncthreads();
    unsigned int p[8];
#pragma unroll
    for (int q = 0; q < 8; ++q)
      p[q] = (unsigned int)tile[cg + 2*q][r] | ((unsigned int)tile[cg + 2*q + 1][r] << 16);
    unsigned short* dst = Vt + hoff + (size_t)(e0 + r) * 2304 + s0 + cg;
    *(uint4*)dst       = make_uint4(p[0], p[1], p[2], p[3]);
    *(uint4*)(dst + 8) = make_uint4(p[4], p[5], p[6], p[7]);
  } else {
    int bb = b - 1728;
    int bx = bb % 48, by = (bb / 48) % 48, z = bb / 2304;
    const float* in = z ? w_add_out : w_out;
    unsigned short* out = z ? wTao : wTo;
    tr_body(in, out, 3072, 3072, bx * 64, by * 64, tile, threadIdx.x);
  }
}

// ---------------------------------------------------------------------------
// merged QKV GEMM: 18 M-tiles (16 spatial K=3072 no-bias, 2 prompt K=1536
// +bias), 72 N-tiles over Nn=9216. Grid 1296 = 8*162.
// ---------------------------------------------------------------------------
__global__ __launch_bounds__(256, 4) void gemm_qkv2(
    const unsigned short* __restrict__ Aspat, const unsigned short* __restrict__ Aprom,
    const unsigned short* __restrict__ Btq, const unsigned short* __restrict__ Btaq,
    const float* __restrict__ biasp, unsigned short* __restrict__ Cout)
{
  __shared__ unsigned short lsA[128 * 64];
  __shared__ unsigned short lsB[128 * 64];
  const int tid = threadIdx.x;
  const int w = tid >> 6, lane = tid & 63;
  const int wr = w >> 1, wc = w & 1;
  const int l15 = lane & 15, lhi = lane >> 4;
  const int wg = blockIdx.x;
  const int swz = (wg & 7) * 162 + (wg >> 3);
  const int bx = swz / 18, by = swz - bx * 18;
  const bool pr = by >= 16;
  const int K = pr ? 1536 : 3072;

  f32x4 acc[4][4];
#pragma unroll
  for (int i = 0; i < 4; ++i)
#pragma unroll
    for (int j = 0; j < 4; ++j) acc[i][j] = (f32x4){0.f, 0.f, 0.f, 0.f};

  int srcoff[4];
#pragma unroll
  for (int j = 0; j < 4; ++j) {
    int c = j * 256 + tid;
    int row = c >> 3;
    int sl = (c & 7) ^ (row & 7);
    srcoff[j] = row * K + sl * 8;
  }
  const int wb = w * 1024;
  const unsigned short* Abase = pr ? (Aprom + (size_t)((by - 16) * 128) * 1536)
                                   : (Aspat + (size_t)(by * 128) * 3072);
  const unsigned short* Bbase = (pr ? Btaq : Btq) + (size_t)(bx * 128) * K;

  for (int k0 = 0; k0 < K; k0 += 64) {
#pragma unroll
    for (int j = 0; j < 4; ++j) {
      gload16(Abase + srcoff[j] + k0, (char*)lsA + j * 4096 + wb);
      gload16(Bbase + srcoff[j] + k0, (char*)lsB + j * 4096 + wb);
    }
    __syncthreads();
#pragma unroll
    for (int kk = 0; kk < 2; ++kk) {
      const int sl = ((kk << 2) + lhi) ^ (l15 & 7);
      short8 af[4], bf[4];
#pragma unroll
      for (int t = 0; t < 4; ++t) {
        af[t] = *(const short8*)((char*)lsA + (wr * 64 + t * 16 + l15) * 128 + (sl << 4));
        bf[t] = *(const short8*)((char*)lsB + (wc * 64 + t * 16 + l15) * 128 + (sl << 4));
      }
#pragma unroll
      for (int mt = 0; mt < 4; ++mt)
#pragma unroll
        for (int nt = 0; nt < 4; ++nt)
          acc[mt][nt] = __builtin_amdgcn_mfma_f32_16x16x32_bf16(af[mt], bf[nt], acc[mt][nt], 0, 0, 0);
    }
    __syncthreads();
  }

  const int nbase = bx * 128 + wc * 64;
  const int mbase = by * 128 + wr * 64;
  float bv[4] = {0.f, 0.f, 0.f, 0.f};
  if (pr) {
#pragma unroll
    for (int nt = 0; nt < 4; ++nt) bv[nt] = biasp[nbase + nt * 16 + l15];
  }
#pragma unroll
  for (int mt = 0; mt < 4; ++mt)
#pragma unroll
    for (int nt = 0; nt < 4; ++nt) {
#pragma unroll
      for (int r2 = 0; r2 < 4; ++r2) {
        int m = mbase + mt * 16 + lhi * 4 + r2;
        int n = nbase + nt * 16 + l15;
        Cout[(size_t)m * 9216 + n] = f2bf(acc[mt][nt][r2] + bv[nt]);
      }
    }
}

// ---------------------------------------------------------------------------
// merged output-projection GEMM: 18 M-tiles, 24 N-tiles, K=3072. Grid 432.
// ---------------------------------------------------------------------------
__global__ __launch_bounds__(256, 4) void gemm_out2(
    const unsigned short* __restrict__ A,
    const unsigned short* __restrict__ Bt0, const float* __restrict__ b0,
    const unsigned short* __restrict__ Bt1, const float* __restrict__ b1,
    float* __restrict__ C)
{
  __shared__ unsigned short lsA[128 * 64];
  __shared__ unsigned short lsB[128 * 64];
  const int tid = threadIdx.x;
  const int w = tid >> 6, lane = tid & 63;
  const int wr = w >> 1, wc = w & 1;
  const int l15 = lane & 15, lhi = lane >> 4;
  const int wg = blockIdx.x;
  const int swz = (wg & 7) * 54 + (wg >> 3);
  const int bx = swz / 18, by = swz - bx * 18;
  const bool pr = by >= 16;

  f32x4 acc[4][4];
#pragma unroll
  for (int i = 0; i < 4; ++i)
#pragma unroll
    for (int j = 0; j < 4; ++j) acc[i][j] = (f32x4){0.f, 0.f, 0.f, 0.f};

  int srcoff[4];
#pragma unroll
  for (int j = 0; j < 4; ++j) {
    int c = j * 256 + tid;
    int row = c >> 3;
    int sl = (c & 7) ^ (row & 7);
    srcoff[j] = row * 3072 + sl * 8;
  }
  const int wb = w * 1024;
  const unsigned short* Abase = A + (size_t)(by * 128) * 3072;
  const unsigned short* Bbase = (pr ? Bt1 : Bt0) + (size_t)(bx * 128) * 3072;
  const float* bias = pr ? b1 : b0;

  for (int k0 = 0; k0 < 3072; k0 += 64) {
#pragma unroll
    for (int j = 0; j < 4; ++j) {
      gload16(Abase + srcoff[j] + k0, (char*)lsA + j * 4096 + wb);
      gload16(Bbase + srcoff[j] + k0, (char*)lsB + j * 4096 + wb);
    }
    __syncthreads();
#pragma unroll
    for (int kk = 0; kk < 2; ++kk) {
      const int sl = ((kk << 2) + lhi) ^ (l15 & 7);
      short8 af[4], bf[4];
#pragma unroll
      for (int t = 0; t < 4; ++t) {
        af[t] = *(const short8*)((char*)lsA + (wr * 64 + t * 16 + l15) * 128 + (sl << 4));
        bf[t] = *(const short8*)((char*)lsB + (wc * 64 + t * 16 + l15) * 128 + (sl << 4));
      }
#pragma unroll
      for (int mt = 0; mt < 4; ++mt)
#pragma unroll
        for (int nt = 0; nt < 4; ++nt)
          acc[mt][nt] = __builtin_amdgcn_mfma_f32_16x16x32_bf16(af[mt], bf[nt], acc[mt][nt], 0, 0, 0);
    }
    __syncthreads();
  }

  const int nbase = bx * 128 + wc * 64;
  const int mbase = by * 128 + wr * 64;
  float bv[4];
#pragma unroll
  for (int nt = 0; nt < 4; ++nt) bv[nt] = bias[nbase + nt * 16 + l15];
#pragma unroll
  for (int mt = 0; mt < 4; ++mt)
#pragma unroll
    for (int nt = 0; nt < 4; ++nt) {
#pragma unroll
      for (int r2 = 0; r2 < 4; ++r2) {
        int m = mbase + mt * 16 + lhi * 4 + r2;
        int n = nbase + nt * 16 + l15;
        C[(size_t)m * 3072 + n] = acc[mt][nt][r2] + bv[nt];
      }
    }
}

// ---------------------------------------------------------------------------
// fused RMSNorm + RoPE + head split/concat
// Q pre-scaled by (1/sqrt(E)) * log2(e): attention softmax runs in exp2 domain
// ---------------------------------------------------------------------------
__global__ __launch_bounds__(256) void fuse_rms_rope(
    const unsigned short* __restrict__ qkv,
    const unsigned short* __restrict__ aqkv,
    const float* __restrict__ nq, const float* __restrict__ nk,
    const float* __restrict__ naq, const float* __restrict__ nak,
    const float* __restrict__ ctab, const float* __restrict__ stab,
    unsigned short* __restrict__ Qf, unsigned short* __restrict__ Kf,
    unsigned short* __restrict__ Vf)
{
  int wid = blockIdx.x * 4 + (threadIdx.x >> 6);
  int lane = threadIdx.x & 63;
  int h = wid / 2304, s = wid % 2304;
  bool sp = (s < 2048);
  const unsigned short* src = sp ? (qkv + (size_t)s * 9216)
                                 : (aqkv + (size_t)(s - 2048) * 9216);
  int e = lane * 2;
  ushort2 qu = *(const ushort2*)&src[h * 128 + e];
  ushort2 ku = *(const ushort2*)&src[3072 + h * 128 + e];
  ushort2 vu = *(const ushort2*)&src[6144 + h * 128 + e];
  float q0 = bf2f(qu.x), q1 = bf2f(qu.y);
  float k0 = bf2f(ku.x), k1 = bf2f(ku.y);
  float sq = q0 * q0 + q1 * q1, sk = k0 * k0 + k1 * k1;
#pragma unroll
  for (int mm = 1; mm < 64; mm <<= 1) {
    sq += __shfl_xor(sq, mm);
    sk += __shfl_xor(sk, mm);
  }
  float rq = rsqrtf(sq * (1.f / 128.f) + 1e-5f);
  float rk = rsqrtf(sk * (1.f / 128.f) + 1e-5f);
  const float* wq = sp ? nq : naq;
  const float* wk = sp ? nk : nak;
  q0 *= rq * wq[e]; q1 *= rq * wq[e + 1];
  k0 *= rk * wk[e]; k1 *= rk * wk[e + 1];
  if (sp) {
    float c0 = ctab[s * 128 + e], c1 = ctab[s * 128 + e + 1];
    float s0 = stab[s * 128 + e], s1 = stab[s * 128 + e + 1];
    float a0 = q0 * c0 - q1 * s0, a1 = q1 * c1 + q0 * s1;
    float b0 = k0 * c0 - k1 * s0, b1 = k1 * c1 + k0 * s1;
    q0 = a0; q1 = a1; k0 = b0; k1 = b1;
  }
  const float scale = 0.08838834764831845f * 1.4426950408889634f;  // 1/sqrt(128)*log2e
  q0 *= scale; q1 *= scale;
  size_t o = (size_t)h * 2304 * 128 + (size_t)s * 128 + e;
  *(ushort2*)&Qf[o] = make_ushort2(f2bf(q0), f2bf(q1));
  *(ushort2*)&Kf[o] = make_ushort2(f2bf(k0), f2bf(k1));
  *(ushort2*)&Vf[o] = vu;
}

// ---------------------------------------------------------------------------
// flash attention (r16, known-good): swapped QK^T on 32x32x16, lazy
// defer-max (exp with current m, reduce/rescale after PV), K/V double-
// buffered + issued together early, one barrier/iter, widened swizzles.
// ---------------------------------------------------------------------------
__global__ __launch_bounds__(256, 2) void attn_fwd(
    const unsigned short* __restrict__ Qf, const unsigned short* __restrict__ Kf,
    const unsigned short* __restrict__ Vt, unsigned short* __restrict__ Om)
{
  __shared__ unsigned short lsK[2][64 * 128];
  __shared__ unsigned short lsV[2][128 * 64];
  int wg = blockIdx.x;
  int swz = (wg & 7) * 54 + (wg >> 3);     // 432 blocks = 8 * 54
  int h = swz / 18, qt = swz - h * 18;
  int q0 = qt * 128;
  int tid = threadIdx.x, w = tid >> 6, lane = tid & 63;
  int l31 = lane & 31, hh = lane >> 5;
  const size_t headO = (size_t)h * 2304 * 128;

  short8 qf[8];
  {
    const unsigned short* qrow = Qf + headO + (size_t)(q0 + w * 32 + l31) * 128 + hh * 8;
#pragma unroll
    for (int s = 0; s < 8; ++s)
      qf[s] = *(const short8*)(qrow + s * 16);
  }

  float m_run = 0.0f, lsum = 0.f;          // lazy defer-max: init 0, not -inf
  f32x16 accO[4];
#pragma unroll
  for (int dt = 0; dt < 4; ++dt)
#pragma unroll
    for (int i = 0; i < 16; ++i) accO[dt][i] = 0.f;

  size_t kGo[4], vGo[4];
  int loff[4];
#pragma unroll
  for (int j = 0; j < 4; ++j) {
    int c = j * 256 + w * 64 + lane;
    int krow = c >> 4, kcol = (c & 15) ^ (krow & 15);
    int sr = c >> 4, lg = (c & 15) ^ (sr & 15);
    int vrow = sr * 2 + (lg >> 3), vcol = lg & 7;
    kGo[j] = (size_t)krow * 128 + kcol * 8;
    vGo[j] = (size_t)vrow * 2304 + vcol * 8;
    loff[j] = (j * 256 + w * 64) * 16;
  }
  const unsigned short* kbase0 = Kf + headO;
  const unsigned short* vbase0 = Vt + headO;

  auto stage = [&](int kb2, int b) {
    const unsigned short* kb_ = kbase0 + (size_t)kb2 * 128;
    const unsigned short* vb_ = vbase0 + kb2;
#pragma unroll
    for (int j = 0; j < 4; ++j) {
      gload16(kb_ + kGo[j], (char*)lsK[b] + loff[j]);
      gload16(vb_ + vGo[j], (char*)lsV[b] + loff[j]);
    }
  };

  stage(0, 0);
  int cur = 0;

  for (int kb = 0; kb < 2304; kb += 64) {
    drain_ldsdma();
    __syncthreads();
    if (kb + 64 < 2304) stage(kb + 64, cur ^ 1);   // issue-early prefetch

    f32x16 accS[2];
#pragma unroll
    for (int t = 0; t < 2; ++t)
#pragma unroll
      for (int i = 0; i < 16; ++i) accS[t][i] = 0.f;
    __builtin_amdgcn_s_setprio(1);
#pragma unroll
    for (int t = 0; t < 2; ++t) {
      const int row = l31 + t * 32;
      const int rsw = row & 15;
#pragma unroll
      for (int s = 0; s < 8; ++s) {
        short8 kfr = *(const short8*)((char*)lsK[cur] + row * 256 +
                        (((s * 2 + hh) ^ rsw) << 4));
        accS[t] = __builtin_amdgcn_mfma_f32_32x32x16_bf16(kfr, qf[s], accS[t], 0, 0, 0);
      }
    }

    // ---- lazy softmax + PV: exp with current m_run, no reduce in between
#pragma unroll
    for (int ks = 0; ks < 4; ++ks) {
      const int t = ks >> 1;
      const int qlo = 8 * (ks & 1);
      float p0 = __builtin_amdgcn_exp2f(accS[t][qlo + 0] - m_run);
      float p1 = __builtin_amdgcn_exp2f(accS[t][qlo + 1] - m_run);
      float p2 = __builtin_amdgcn_exp2f(accS[t][qlo + 2] - m_run);
      float p3 = __builtin_amdgcn_exp2f(accS[t][qlo + 3] - m_run);
      float p4 = __builtin_amdgcn_exp2f(accS[t][qlo + 4] - m_run);
      float p5 = __builtin_amdgcn_exp2f(accS[t][qlo + 5] - m_run);
      float p6 = __builtin_amdgcn_exp2f(accS[t][qlo + 6] - m_run);
      float p7 = __builtin_amdgcn_exp2f(accS[t][qlo + 7] - m_run);
      lsum += ((p0 + p1) + (p2 + p3)) + ((p4 + p5) + (p6 + p7));
      unsigned int wlo0 = pk2(p0, p1);
      unsigned int wlo1 = pk2(p2, p3);
      unsigned int whi0 = pk2(p4, p5);
      unsigned int whi1 = pk2(p6, p7);
      unsigned int r0 = __shfl_xor(hh ? wlo0 : whi0, 32);
      unsigned int r1 = __shfl_xor(hh ? wlo1 : whi1, 32);
      unsigned int fw0 = hh ? r0 : wlo0;
      unsigned int fw1 = hh ? r1 : wlo1;
      unsigned int fw2 = hh ? whi0 : r0;
      unsigned int fw3 = hh ? whi1 : r1;
      unsigned int fwa[4] = {fw0, fw1, fw2, fw3};
      short8 paf = *(short8*)fwa;
#pragma unroll
      for (int dt = 0; dt < 4; ++dt) {
        const int row = dt * 32 + l31;
        const int sr = row >> 1;
        const int g = (((row & 1) << 3) | (ks * 2 + hh)) ^ (sr & 15);
        short8 vfr = *(const short8*)((char*)lsV[cur] + sr * 256 + (g << 4));
        accO[dt] = __builtin_amdgcn_mfma_f32_32x32x16_bf16(paf, vfr, accO[dt], 0, 0, 0);
      }
    }
    __builtin_amdgcn_s_setprio(0);

    // ---- deferred max/gate/rescale (off the QK->PV critical path)
    float lm = accS[0][0];
#pragma unroll
    for (int t = 0; t < 2; ++t)
#pragma unroll
      for (int i = 0; i < 16; ++i) lm = fmaxf(lm, accS[t][i]);
    float lmx = fmaxf(lm, __shfl_xor(lm, 32));
    if (!__all(lmx <= m_run + 11.0f)) {
      float mnew = fmaxf(m_run, lmx);
      float corr = __builtin_amdgcn_exp2f(m_run - mnew);
      lsum *= corr;
      float corrq[16];
#pragma unroll
      for (int r = 0; r < 16; ++r)
        corrq[r] = __shfl(corr, ((r & 3) + 8 * (r >> 2) + 4 * hh) | (lane & 32));
#pragma unroll
      for (int dt = 0; dt < 4; ++dt)
#pragma unroll
        for (int r = 0; r < 16; ++r) accO[dt][r] *= corrq[r];
      m_run = mnew;
    }
    cur ^= 1;
  }

  lsum += __shfl_xor(lsum, 32);
  float inv = 1.0f / lsum;
  float invq[16];
#pragma unroll
  for (int r = 0; r < 16; ++r)
    invq[r] = __shfl(inv, ((r & 3) + 8 * (r >> 2) + 4 * hh) | (lane & 32));
#pragma unroll
  for (int dt = 0; dt < 4; ++dt)
#pragma unroll
    for (int r = 0; r < 16; ++r) {
      int qrow = (r & 3) + 8 * (r >> 2) + 4 * hh;
      int row = q0 + w * 32 + qrow;
      Om[(size_t)row * 3072 + h * 128 + dt * 32 + l31] = f2bf(accO[dt][r] * invq[r]);
    }
}

// ---------------------------------------------------------------------------
extern "C" void kernel_launch(void* const* d_in, const int* in_sizes, int n_in,
                              void* d_out, int out_size, void* d_ws, size_t ws_size,
                              hipStream_t stream)
{
  const float* spatial      = (const float*)d_in[0];
  const float* prompt       = (const float*)d_in[1];
  const float* w_qkv        = (const float*)d_in[2];
  const float* w_add_qkv    = (const float*)d_in[3];
  const float* b_add_qkv    = (const float*)d_in[4];
  const float* norm_q_w     = (const float*)d_in[5];
  const float* norm_k_w     = (const float*)d_in[6];
  const float* norm_add_q_w = (const float*)d_in[7];
  const float* norm_add_k_w = (const float*)d_in[8];
  const float* w_out        = (const float*)d_in[9];
  const float* b_out        = (const float*)d_in[10];
  const float* w_add_out    = (const float*)d_in[11];
  const float* b_add_out    = (const float*)d_in[12];
  const float* rope_cos     = (const float*)d_in[13];
  const float* rope_sin     = (const float*)d_in[14];

  constexpr size_t O_WTQ  = 0;
  constexpr size_t O_WTAQ = 56623104;
  constexpr size_t O_SPAT = 84934656;
  constexpr size_t O_PROM = 97517568;
  constexpr size_t O_QKV  = 98304000;
  constexpr size_t O_AQKV = 136052736;
  constexpr size_t O_QF   = 140771328;
  constexpr size_t O_KF   = 154927104;
  constexpr size_t O_VF   = 169082880;
  constexpr size_t TOTAL  = 183238656;
  constexpr size_t O_WTO  = O_WTQ;                 // reuse AFTER gemm_qkv2
  constexpr size_t O_WTAO = O_WTQ + 18874368;
  constexpr size_t O_VT   = O_QKV;                 // reuse after fuse_rms_rope
  constexpr size_t O_ATTN = O_WTAQ;                // reuse after gemm_qkv2
  if (ws_size < TOTAL) return;

  char* ws = (char*)d_ws;
  unsigned short* wTq      = (unsigned short*)(ws + O_WTQ);
  unsigned short* wTaq     = (unsigned short*)(ws + O_WTAQ);
  unsigned short* spat_bf  = (unsigned short*)(ws + O_SPAT);
  unsigned short* prom_bf  = (unsigned short*)(ws + O_PROM);
  unsigned short* qkv_s    = (unsigned short*)(ws + O_QKV);
  unsigned short* aqkv     = (unsigned short*)(ws + O_AQKV);
  unsigned short* Qf       = (unsigned short*)(ws + O_QF);
  unsigned short* Kf       = (unsigned short*)(ws + O_KF);
  unsigned short* Vf       = (unsigned short*)(ws + O_VF);
  unsigned short* wTo      = (unsigned short*)(ws + O_WTO);
  unsigned short* wTao     = (unsigned short*)(ws + O_WTAO);
  unsigned short* Vt       = (unsigned short*)(ws + O_VT);
  unsigned short* attn_out = (unsigned short*)(ws + O_ATTN);

  prep<<<12416, 256, 0, stream>>>(spatial, spat_bf, prompt, prom_bf,
                                  w_qkv, w_add_qkv, wTq, wTaq);
  gemm_qkv2<<<1296, 256, 0, stream>>>(spat_bf, prom_bf, wTq, wTaq, b_add_qkv, qkv_s);
  fuse_rms_rope<<<13824, 256, 0, stream>>>(qkv_s, aqkv, norm_q_w, norm_k_w,
                                           norm_add_q_w, norm_add_k_w,
                                           rope_cos, rope_sin, Qf, Kf, Vf);
  posttrans<<<6336, 256, 0, stream>>>(Vf, Vt, w_out, w_add_out, wTo, wTao);
  attn_fwd<<<432, 256, 0, stream>>>(Qf, Kf, Vt, attn_out);
  gemm_out2<<<432, 256, 0, stream>>>(attn_out, wTo, b_out, wTao, b_add_out,
                                     (float*)d_out);
}

// Round 20
// 388.953 us; speedup vs baseline: 1.0250x; 1.0250x over previous
//
#include <hip/hip_runtime.h>
#include <cstdint>
#include <cstddef>

typedef __attribute__((ext_vector_type(8))) short short8;
typedef __attribute__((ext_vector_type(4))) float f32x4;
typedef __attribute__((ext_vector_type(16))) float f32x16;

#define DEVI static __device__ __forceinline__

DEVI float bf2f(unsigned short b) {
  union { unsigned int u; float f; } v; v.u = ((unsigned int)b) << 16; return v.f;
}
DEVI unsigned short f2bf(float f) {
  union { float f; unsigned int u; } v; v.f = f;
  unsigned int r = v.u + 0x7fffu + ((v.u >> 16) & 1u);   // RTNE
  return (unsigned short)(r >> 16);
}
// pack two positive floats to bf16x2, round-half-up
DEVI unsigned int pk2(float a, float b) {
  union { float f; unsigned int u; } ua, ub; ua.f = a; ub.f = b;
  return ((ua.u + 0x8000u) >> 16) | ((ub.u + 0x8000u) & 0xffff0000u);
}

DEVI void gload16(const void* g, void* l) {
  __builtin_amdgcn_global_load_lds(
      (const __attribute__((address_space(1))) void*)g,
      (__attribute__((address_space(3))) void*)l, 16, 0, 0);
}

DEVI void drain_ldsdma() {
  asm volatile("s_waitcnt vmcnt(0)" ::: "memory");
  __builtin_amdgcn_sched_barrier(0);
}

// ---------------------------------------------------------------------------
// transpose + convert body: in f32 [Kd][Nd] -> out bf16 [Nd][Kd], 64x64 tile
// ---------------------------------------------------------------------------
DEVI void tr_body(const float* in, unsigned short* out, int Kd, int Nd,
                  int n0, int k0, unsigned short (*tile)[72], int t)
{
  int r = t >> 2, cg = (t & 3) * 16;
  const float* src = in + (size_t)(k0 + r) * Nd + n0 + cg;
#pragma unroll
  for (int q = 0; q < 16; q += 4) {
    float4 f = *(const float4*)(src + q);
    ushort4 u;
    u.x = f2bf(f.x); u.y = f2bf(f.y); u.z = f2bf(f.z); u.w = f2bf(f.w);
    *(ushort4*)&tile[r][cg + q] = u;
  }
  __syncthreads();
  unsigned int p[8];
#pragma unroll
  for (int q = 0; q < 8; ++q)
    p[q] = (unsigned int)tile[cg + 2*q][r] | ((unsigned int)tile[cg + 2*q + 1][r] << 16);
  unsigned short* dst = out + (size_t)(n0 + r) * Kd + k0 + cg;
  *(uint4*)dst       = make_uint4(p[0], p[1], p[2], p[3]);
  *(uint4*)(dst + 8) = make_uint4(p[4], p[5], p[6], p[7]);
}

// ---------------------------------------------------------------------------
// merged preprocessing:
//   [0,2048)       f32->bf16 converts (grid-stride)
//   [2048,12416)   w_qkv / w_add_qkv transpose
// ---------------------------------------------------------------------------
__global__ __launch_bounds__(256) void prep(
    const float* __restrict__ spatial, unsigned short* __restrict__ spat_bf,
    const float* __restrict__ prompt,  unsigned short* __restrict__ prom_bf,
    const float* __restrict__ w_qkv,   const float* __restrict__ w_add_qkv,
    unsigned short* __restrict__ wTq,  unsigned short* __restrict__ wTaq)
{
  __shared__ unsigned short tile[64][72];
  const int b = blockIdx.x;
  if (b < 2048) {
    const int n4a = 2048 * 3072 / 4, n4b = 256 * 1536 / 4;
    int i = b * 256 + threadIdx.x;
    int stride = 2048 * 256;
    int total = n4a + n4b;
    for (; i < total; i += stride) {
      const float4* src = (i < n4a) ? &((const float4*)spatial)[i]
                                    : &((const float4*)prompt)[i - n4a];
      ushort4* dst = (i < n4a) ? &((ushort4*)spat_bf)[i] : &((ushort4*)prom_bf)[i - n4a];
      float4 f = *src;
      ushort4 u;
      u.x = f2bf(f.x); u.y = f2bf(f.y); u.z = f2bf(f.z); u.w = f2bf(f.w);
      *dst = u;
    }
  } else {
    int bb = b - 2048;
    int bx = bb % 144, y = bb / 144;
    const float* in;  unsigned short* out;  int Kd, k0;
    if (y < 48) { in = w_qkv;     out = wTq;  Kd = 3072; k0 = y * 64; }
    else        { in = w_add_qkv; out = wTaq; Kd = 1536; k0 = (y - 48) * 64; }
    tr_body(in, out, Kd, 9216, bx * 64, k0, tile, threadIdx.x);
  }
}

// merged out-weight transposes: MUST launch after gemm_qkv2 (aliases wTq).
__global__ __launch_bounds__(256) void transpose_wout(
    const float* __restrict__ w_out, const float* __restrict__ w_add_out,
    unsigned short* __restrict__ wTo, unsigned short* __restrict__ wTao)
{
  __shared__ unsigned short tile[64][72];
  const float* in = blockIdx.z ? w_add_out : w_out;
  unsigned short* out = blockIdx.z ? wTao : wTo;
  tr_body(in, out, 3072, 3072, blockIdx.x * 64, blockIdx.y * 64, tile, threadIdx.x);
}

// ---------------------------------------------------------------------------
// bf16 transpose per head: in [rows][cols] -> out [cols][rows], 64x64 tiles
// ---------------------------------------------------------------------------
__global__ __launch_bounds__(256) void transpose_bf16_64(
    const unsigned short* __restrict__ in, unsigned short* __restrict__ out,
    int rows, int cols)
{
  __shared__ unsigned short tile[64][72];
  size_t hoff = (size_t)blockIdx.z * rows * cols;
  int e0 = blockIdx.x * 64, s0 = blockIdx.y * 64;
  int t = threadIdx.x;
  int r = t >> 2, cg = (t & 3) * 16;
  const unsigned short* src = in + hoff + (size_t)(s0 + r) * cols + e0 + cg;
  *(uint4*)&tile[r][cg]     = *(const uint4*)src;
  *(uint4*)&tile[r][cg + 8] = *(const uint4*)(src + 8);
  __syncthreads();
  unsigned int p[8];
#pragma unroll
  for (int q = 0; q < 8; ++q)
    p[q] = (unsigned int)tile[cg + 2*q][r] | ((unsigned int)tile[cg + 2*q + 1][r] << 16);
  unsigned short* dst = out + hoff + (size_t)(e0 + r) * rows + s0 + cg;
  *(uint4*)dst       = make_uint4(p[0], p[1], p[2], p[3]);
  *(uint4*)(dst + 8) = make_uint4(p[4], p[5], p[6], p[7]);
}

// ---------------------------------------------------------------------------
// merged QKV GEMM: 18 M-tiles (16 spatial K=3072 no-bias, 2 prompt K=1536
// +bias), 72 N-tiles over Nn=9216. Grid 1296 = 8*162.
// ---------------------------------------------------------------------------
__global__ __launch_bounds__(256, 4) void gemm_qkv2(
    const unsigned short* __restrict__ Aspat, const unsigned short* __restrict__ Aprom,
    const unsigned short* __restrict__ Btq, const unsigned short* __restrict__ Btaq,
    const float* __restrict__ biasp, unsigned short* __restrict__ Cout)
{
  __shared__ unsigned short lsA[128 * 64];
  __shared__ unsigned short lsB[128 * 64];
  const int tid = threadIdx.x;
  const int w = tid >> 6, lane = tid & 63;
  const int wr = w >> 1, wc = w & 1;
  const int l15 = lane & 15, lhi = lane >> 4;
  const int wg = blockIdx.x;
  const int swz = (wg & 7) * 162 + (wg >> 3);
  const int bx = swz / 18, by = swz - bx * 18;
  const bool pr = by >= 16;
  const int K = pr ? 1536 : 3072;

  f32x4 acc[4][4];
#pragma unroll
  for (int i = 0; i < 4; ++i)
#pragma unroll
    for (int j = 0; j < 4; ++j) acc[i][j] = (f32x4){0.f, 0.f, 0.f, 0.f};

  int srcoff[4];
#pragma unroll
  for (int j = 0; j < 4; ++j) {
    int c = j * 256 + tid;
    int row = c >> 3;
    int sl = (c & 7) ^ (row & 7);
    srcoff[j] = row * K + sl * 8;
  }
  const int wb = w * 1024;
  const unsigned short* Abase = pr ? (Aprom + (size_t)((by - 16) * 128) * 1536)
                                   : (Aspat + (size_t)(by * 128) * 3072);
  const unsigned short* Bbase = (pr ? Btaq : Btq) + (size_t)(bx * 128) * K;

  for (int k0 = 0; k0 < K; k0 += 64) {
#pragma unroll
    for (int j = 0; j < 4; ++j) {
      gload16(Abase + srcoff[j] + k0, (char*)lsA + j * 4096 + wb);
      gload16(Bbase + srcoff[j] + k0, (char*)lsB + j * 4096 + wb);
    }
    __syncthreads();
#pragma unroll
    for (int kk = 0; kk < 2; ++kk) {
      const int sl = ((kk << 2) + lhi) ^ (l15 & 7);
      short8 af[4], bf[4];
#pragma unroll
      for (int t = 0; t < 4; ++t) {
        af[t] = *(const short8*)((char*)lsA + (wr * 64 + t * 16 + l15) * 128 + (sl << 4));
        bf[t] = *(const short8*)((char*)lsB + (wc * 64 + t * 16 + l15) * 128 + (sl << 4));
      }
#pragma unroll
      for (int mt = 0; mt < 4; ++mt)
#pragma unroll
        for (int nt = 0; nt < 4; ++nt)
          acc[mt][nt] = __builtin_amdgcn_mfma_f32_16x16x32_bf16(af[mt], bf[nt], acc[mt][nt], 0, 0, 0);
    }
    __syncthreads();
  }

  const int nbase = bx * 128 + wc * 64;
  const int mbase = by * 128 + wr * 64;
  float bv[4] = {0.f, 0.f, 0.f, 0.f};
  if (pr) {
#pragma unroll
    for (int nt = 0; nt < 4; ++nt) bv[nt] = biasp[nbase + nt * 16 + l15];
  }
#pragma unroll
  for (int mt = 0; mt < 4; ++mt)
#pragma unroll
    for (int nt = 0; nt < 4; ++nt) {
#pragma unroll
      for (int r2 = 0; r2 < 4; ++r2) {
        int m = mbase + mt * 16 + lhi * 4 + r2;
        int n = nbase + nt * 16 + l15;
        Cout[(size_t)m * 9216 + n] = f2bf(acc[mt][nt][r2] + bv[nt]);
      }
    }
}

// ---------------------------------------------------------------------------
// merged output-projection GEMM: 18 M-tiles, 24 N-tiles, K=3072. Grid 432.
// ---------------------------------------------------------------------------
__global__ __launch_bounds__(256, 4) void gemm_out2(
    const unsigned short* __restrict__ A,
    const unsigned short* __restrict__ Bt0, const float* __restrict__ b0,
    const unsigned short* __restrict__ Bt1, const float* __restrict__ b1,
    float* __restrict__ C)
{
  __shared__ unsigned short lsA[128 * 64];
  __shared__ unsigned short lsB[128 * 64];
  const int tid = threadIdx.x;
  const int w = tid >> 6, lane = tid & 63;
  const int wr = w >> 1, wc = w & 1;
  const int l15 = lane & 15, lhi = lane >> 4;
  const int wg = blockIdx.x;
  const int swz = (wg & 7) * 54 + (wg >> 3);
  const int bx = swz / 18, by = swz - bx * 18;
  const bool pr = by >= 16;

  f32x4 acc[4][4];
#pragma unroll
  for (int i = 0; i < 4; ++i)
#pragma unroll
    for (int j = 0; j < 4; ++j) acc[i][j] = (f32x4){0.f, 0.f, 0.f, 0.f};

  int srcoff[4];
#pragma unroll
  for (int j = 0; j < 4; ++j) {
    int c = j * 256 + tid;
    int row = c >> 3;
    int sl = (c & 7) ^ (row & 7);
    srcoff[j] = row * 3072 + sl * 8;
  }
  const int wb = w * 1024;
  const unsigned short* Abase = A + (size_t)(by * 128) * 3072;
  const unsigned short* Bbase = (pr ? Bt1 : Bt0) + (size_t)(bx * 128) * 3072;
  const float* bias = pr ? b1 : b0;

  for (int k0 = 0; k0 < 3072; k0 += 64) {
#pragma unroll
    for (int j = 0; j < 4; ++j) {
      gload16(Abase + srcoff[j] + k0, (char*)lsA + j * 4096 + wb);
      gload16(Bbase + srcoff[j] + k0, (char*)lsB + j * 4096 + wb);
    }
    __syncthreads();
#pragma unroll
    for (int kk = 0; kk < 2; ++kk) {
      const int sl = ((kk << 2) + lhi) ^ (l15 & 7);
      short8 af[4], bf[4];
#pragma unroll
      for (int t = 0; t < 4; ++t) {
        af[t] = *(const short8*)((char*)lsA + (wr * 64 + t * 16 + l15) * 128 + (sl << 4));
        bf[t] = *(const short8*)((char*)lsB + (wc * 64 + t * 16 + l15) * 128 + (sl << 4));
      }
#pragma unroll
      for (int mt = 0; mt < 4; ++mt)
#pragma unroll
        for (int nt = 0; nt < 4; ++nt)
          acc[mt][nt] = __builtin_amdgcn_mfma_f32_16x16x32_bf16(af[mt], bf[nt], acc[mt][nt], 0, 0, 0);
    }
    __syncthreads();
  }

  const int nbase = bx * 128 + wc * 64;
  const int mbase = by * 128 + wr * 64;
  float bv[4];
#pragma unroll
  for (int nt = 0; nt < 4; ++nt) bv[nt] = bias[nbase + nt * 16 + l15];
#pragma unroll
  for (int mt = 0; mt < 4; ++mt)
#pragma unroll
    for (int nt = 0; nt < 4; ++nt) {
#pragma unroll
      for (int r2 = 0; r2 < 4; ++r2) {
        int m = mbase + mt * 16 + lhi * 4 + r2;
        int n = nbase + nt * 16 + l15;
        C[(size_t)m * 3072 + n] = acc[mt][nt][r2] + bv[nt];
      }
    }
}

// ---------------------------------------------------------------------------
// fused RMSNorm + RoPE + head split/concat
// Q pre-scaled by (1/sqrt(E)) * log2(e): attention softmax runs in exp2 domain
// ---------------------------------------------------------------------------
__global__ __launch_bounds__(256) void fuse_rms_rope(
    const unsigned short* __restrict__ qkv,
    const unsigned short* __restrict__ aqkv,
    const float* __restrict__ nq, const float* __restrict__ nk,
    const float* __restrict__ naq, const float* __restrict__ nak,
    const float* __restrict__ ctab, const float* __restrict__ stab,
    unsigned short* __restrict__ Qf, unsigned short* __restrict__ Kf,
    unsigned short* __restrict__ Vf)
{
  int wid = blockIdx.x * 4 + (threadIdx.x >> 6);
  int lane = threadIdx.x & 63;
  int h = wid / 2304, s = wid % 2304;
  bool sp = (s < 2048);
  const unsigned short* src = sp ? (qkv + (size_t)s * 9216)
                                 : (aqkv + (size_t)(s - 2048) * 9216);
  int e = lane * 2;
  ushort2 qu = *(const ushort2*)&src[h * 128 + e];
  ushort2 ku = *(const ushort2*)&src[3072 + h * 128 + e];
  ushort2 vu = *(const ushort2*)&src[6144 + h * 128 + e];
  float q0 = bf2f(qu.x), q1 = bf2f(qu.y);
  float k0 = bf2f(ku.x), k1 = bf2f(ku.y);
  float sq = q0 * q0 + q1 * q1, sk = k0 * k0 + k1 * k1;
#pragma unroll
  for (int mm = 1; mm < 64; mm <<= 1) {
    sq += __shfl_xor(sq, mm);
    sk += __shfl_xor(sk, mm);
  }
  float rq = rsqrtf(sq * (1.f / 128.f) + 1e-5f);
  float rk = rsqrtf(sk * (1.f / 128.f) + 1e-5f);
  const float* wq = sp ? nq : naq;
  const float* wk = sp ? nk : nak;
  q0 *= rq * wq[e]; q1 *= rq * wq[e + 1];
  k0 *= rk * wk[e]; k1 *= rk * wk[e + 1];
  if (sp) {
    float c0 = ctab[s * 128 + e], c1 = ctab[s * 128 + e + 1];
    float s0 = stab[s * 128 + e], s1 = stab[s * 128 + e + 1];
    float a0 = q0 * c0 - q1 * s0, a1 = q1 * c1 + q0 * s1;
    float b0 = k0 * c0 - k1 * s0, b1 = k1 * c1 + k0 * s1;
    q0 = a0; q1 = a1; k0 = b0; k1 = b1;
  }
  const float scale = 0.08838834764831845f * 1.4426950408889634f;  // 1/sqrt(128)*log2e
  q0 *= scale; q1 *= scale;
  size_t o = (size_t)h * 2304 * 128 + (size_t)s * 128 + e;
  *(ushort2*)&Qf[o] = make_ushort2(f2bf(q0), f2bf(q1));
  *(ushort2*)&Kf[o] = make_ushort2(f2bf(k0), f2bf(k1));
  *(ushort2*)&Vf[o] = vu;
}

// ---------------------------------------------------------------------------
// flash attention (r16, known-good): swapped QK^T on 32x32x16, lazy
// defer-max (exp with current m, reduce/rescale after PV), K/V double-
// buffered + issued together early, one barrier/iter, widened swizzles.
// ---------------------------------------------------------------------------
__global__ __launch_bounds__(256, 2) void attn_fwd(
    const unsigned short* __restrict__ Qf, const unsigned short* __restrict__ Kf,
    const unsigned short* __restrict__ Vt, unsigned short* __restrict__ Om)
{
  __shared__ unsigned short lsK[2][64 * 128];
  __shared__ unsigned short lsV[2][128 * 64];
  int wg = blockIdx.x;
  int swz = (wg & 7) * 54 + (wg >> 3);     // 432 blocks = 8 * 54
  int h = swz / 18, qt = swz - h * 18;
  int q0 = qt * 128;
  int tid = threadIdx.x, w = tid >> 6, lane = tid & 63;
  int l31 = lane & 31, hh = lane >> 5;
  const size_t headO = (size_t)h * 2304 * 128;

  short8 qf[8];
  {
    const unsigned short* qrow = Qf + headO + (size_t)(q0 + w * 32 + l31) * 128 + hh * 8;
#pragma unroll
    for (int s = 0; s < 8; ++s)
      qf[s] = *(const short8*)(qrow + s * 16);
  }

  float m_run = 0.0f, lsum = 0.f;          // lazy defer-max: init 0, not -inf
  f32x16 accO[4];
#pragma unroll
  for (int dt = 0; dt < 4; ++dt)
#pragma unroll
    for (int i = 0; i < 16; ++i) accO[dt][i] = 0.f;

  size_t kGo[4], vGo[4];
  int loff[4];
#pragma unroll
  for (int j = 0; j < 4; ++j) {
    int c = j * 256 + w * 64 + lane;
    int krow = c >> 4, kcol = (c & 15) ^ (krow & 15);
    int sr = c >> 4, lg = (c & 15) ^ (sr & 15);
    int vrow = sr * 2 + (lg >> 3), vcol = lg & 7;
    kGo[j] = (size_t)krow * 128 + kcol * 8;
    vGo[j] = (size_t)vrow * 2304 + vcol * 8;
    loff[j] = (j * 256 + w * 64) * 16;
  }
  const unsigned short* kbase0 = Kf + headO;
  const unsigned short* vbase0 = Vt + headO;

  auto stage = [&](int kb2, int b) {
    const unsigned short* kb_ = kbase0 + (size_t)kb2 * 128;
    const unsigned short* vb_ = vbase0 + kb2;
#pragma unroll
    for (int j = 0; j < 4; ++j) {
      gload16(kb_ + kGo[j], (char*)lsK[b] + loff[j]);
      gload16(vb_ + vGo[j], (char*)lsV[b] + loff[j]);
    }
  };

  stage(0, 0);
  int cur = 0;

  for (int kb = 0; kb < 2304; kb += 64) {
    drain_ldsdma();
    __syncthreads();
    if (kb + 64 < 2304) stage(kb + 64, cur ^ 1);   // issue-early prefetch

    f32x16 accS[2];
#pragma unroll
    for (int t = 0; t < 2; ++t)
#pragma unroll
      for (int i = 0; i < 16; ++i) accS[t][i] = 0.f;
    __builtin_amdgcn_s_setprio(1);
#pragma unroll
    for (int t = 0; t < 2; ++t) {
      const int row = l31 + t * 32;
      const int rsw = row & 15;
#pragma unroll
      for (int s = 0; s < 8; ++s) {
        short8 kfr = *(const short8*)((char*)lsK[cur] + row * 256 +
                        (((s * 2 + hh) ^ rsw) << 4));
        accS[t] = __builtin_amdgcn_mfma_f32_32x32x16_bf16(kfr, qf[s], accS[t], 0, 0, 0);
      }
    }

    // ---- lazy softmax + PV: exp with current m_run, no reduce in between
#pragma unroll
    for (int ks = 0; ks < 4; ++ks) {
      const int t = ks >> 1;
      const int qlo = 8 * (ks & 1);
      float p0 = __builtin_amdgcn_exp2f(accS[t][qlo + 0] - m_run);
      float p1 = __builtin_amdgcn_exp2f(accS[t][qlo + 1] - m_run);
      float p2 = __builtin_amdgcn_exp2f(accS[t][qlo + 2] - m_run);
      float p3 = __builtin_amdgcn_exp2f(accS[t][qlo + 3] - m_run);
      float p4 = __builtin_amdgcn_exp2f(accS[t][qlo + 4] - m_run);
      float p5 = __builtin_amdgcn_exp2f(accS[t][qlo + 5] - m_run);
      float p6 = __builtin_amdgcn_exp2f(accS[t][qlo + 6] - m_run);
      float p7 = __builtin_amdgcn_exp2f(accS[t][qlo + 7] - m_run);
      lsum += ((p0 + p1) + (p2 + p3)) + ((p4 + p5) + (p6 + p7));
      unsigned int wlo0 = pk2(p0, p1);
      unsigned int wlo1 = pk2(p2, p3);
      unsigned int whi0 = pk2(p4, p5);
      unsigned int whi1 = pk2(p6, p7);
      unsigned int r0 = __shfl_xor(hh ? wlo0 : whi0, 32);
      unsigned int r1 = __shfl_xor(hh ? wlo1 : whi1, 32);
      unsigned int fw0 = hh ? r0 : wlo0;
      unsigned int fw1 = hh ? r1 : wlo1;
      unsigned int fw2 = hh ? whi0 : r0;
      unsigned int fw3 = hh ? whi1 : r1;
      unsigned int fwa[4] = {fw0, fw1, fw2, fw3};
      short8 paf = *(short8*)fwa;
#pragma unroll
      for (int dt = 0; dt < 4; ++dt) {
        const int row = dt * 32 + l31;
        const int sr = row >> 1;
        const int g = (((row & 1) << 3) | (ks * 2 + hh)) ^ (sr & 15);
        short8 vfr = *(const short8*)((char*)lsV[cur] + sr * 256 + (g << 4));
        accO[dt] = __builtin_amdgcn_mfma_f32_32x32x16_bf16(paf, vfr, accO[dt], 0, 0, 0);
      }
    }
    __builtin_amdgcn_s_setprio(0);

    // ---- deferred max/gate/rescale (off the QK->PV critical path)
    float lm = accS[0][0];
#pragma unroll
    for (int t = 0; t < 2; ++t)
#pragma unroll
      for (int i = 0; i < 16; ++i) lm = fmaxf(lm, accS[t][i]);
    float lmx = fmaxf(lm, __shfl_xor(lm, 32));
    if (!__all(lmx <= m_run + 11.0f)) {
      float mnew = fmaxf(m_run, lmx);
      float corr = __builtin_amdgcn_exp2f(m_run - mnew);
      lsum *= corr;
      float corrq[16];
#pragma unroll
      for (int r = 0; r < 16; ++r)
        corrq[r] = __shfl(corr, ((r & 3) + 8 * (r >> 2) + 4 * hh) | (lane & 32));
#pragma unroll
      for (int dt = 0; dt < 4; ++dt)
#pragma unroll
        for (int r = 0; r < 16; ++r) accO[dt][r] *= corrq[r];
      m_run = mnew;
    }
    cur ^= 1;
  }

  lsum += __shfl_xor(lsum, 32);
  float inv = 1.0f / lsum;
  float invq[16];
#pragma unroll
  for (int r = 0; r < 16; ++r)
    invq[r] = __shfl(inv, ((r & 3) + 8 * (r >> 2) + 4 * hh) | (lane & 32));
#pragma unroll
  for (int dt = 0; dt < 4; ++dt)
#pragma unroll
    for (int r = 0; r < 16; ++r) {
      int qrow = (r & 3) + 8 * (r >> 2) + 4 * hh;
      int row = q0 + w * 32 + qrow;
      Om[(size_t)row * 3072 + h * 128 + dt * 32 + l31] = f2bf(accO[dt][r] * invq[r]);
    }
}

// ---------------------------------------------------------------------------
extern "C" void kernel_launch(void* const* d_in, const int* in_sizes, int n_in,
                              void* d_out, int out_size, void* d_ws, size_t ws_size,
                              hipStream_t stream)
{
  const float* spatial      = (const float*)d_in[0];
  const float* prompt       = (const float*)d_in[1];
  const float* w_qkv        = (const float*)d_in[2];
  const float* w_add_qkv    = (const float*)d_in[3];
  const float* b_add_qkv    = (const float*)d_in[4];
  const float* norm_q_w     = (const float*)d_in[5];
  const float* norm_k_w     = (const float*)d_in[6];
  const float* norm_add_q_w = (const float*)d_in[7];
  const float* norm_add_k_w = (const float*)d_in[8];
  const float* w_out        = (const float*)d_in[9];
  const float* b_out        = (const float*)d_in[10];
  const float* w_add_out    = (const float*)d_in[11];
  const float* b_add_out    = (const float*)d_in[12];
  const float* rope_cos     = (const float*)d_in[13];
  const float* rope_sin     = (const float*)d_in[14];

  constexpr size_t O_WTQ  = 0;
  constexpr size_t O_WTAQ = 56623104;
  constexpr size_t O_SPAT = 84934656;
  constexpr size_t O_PROM = 97517568;
  constexpr size_t O_QKV  = 98304000;
  constexpr size_t O_AQKV = 136052736;
  constexpr size_t O_QF   = 140771328;
  constexpr size_t O_KF   = 154927104;
  constexpr size_t O_VF   = 169082880;
  constexpr size_t TOTAL  = 183238656;
  constexpr size_t O_WTO  = O_WTQ;                 // reuse AFTER gemm_qkv2
  constexpr size_t O_WTAO = O_WTQ + 18874368;
  constexpr size_t O_VT   = O_QKV;                 // reuse after fuse_rms_rope
  constexpr size_t O_ATTN = O_WTAQ;                // reuse after gemm_qkv2
  if (ws_size < TOTAL) return;

  char* ws = (char*)d_ws;
  unsigned short* wTq      = (unsigned short*)(ws + O_WTQ);
  unsigned short* wTaq     = (unsigned short*)(ws + O_WTAQ);
  unsigned short* spat_bf  = (unsigned short*)(ws + O_SPAT);
  unsigned short* prom_bf  = (unsigned short*)(ws + O_PROM);
  unsigned short* qkv_s    = (unsigned short*)(ws + O_QKV);
  unsigned short* aqkv     = (unsigned short*)(ws + O_AQKV);
  unsigned short* Qf       = (unsigned short*)(ws + O_QF);
  unsigned short* Kf       = (unsigned short*)(ws + O_KF);
  unsigned short* Vf       = (unsigned short*)(ws + O_VF);
  unsigned short* wTo      = (unsigned short*)(ws + O_WTO);
  unsigned short* wTao     = (unsigned short*)(ws + O_WTAO);
  unsigned short* Vt       = (unsigned short*)(ws + O_VT);
  unsigned short* attn_out = (unsigned short*)(ws + O_ATTN);

  prep<<<12416, 256, 0, stream>>>(spatial, spat_bf, prompt, prom_bf,
                                  w_qkv, w_add_qkv, wTq, wTaq);
  gemm_qkv2<<<1296, 256, 0, stream>>>(spat_bf, prom_bf, wTq, wTaq, b_add_qkv, qkv_s);
  fuse_rms_rope<<<13824, 256, 0, stream>>>(qkv_s, aqkv, norm_q_w, norm_k_w,
                                           norm_add_q_w, norm_add_k_w,
                                           rope_cos, rope_sin, Qf, Kf, Vf);
  transpose_bf16_64<<<dim3(2, 36, 24), 256, 0, stream>>>(Vf, Vt, 2304, 128);
  attn_fwd<<<432, 256, 0, stream>>>(Qf, Kf, Vt, attn_out);
  transpose_wout<<<dim3(48, 48, 2), 256, 0, stream>>>(w_out, w_add_out, wTo, wTao);
  gemm_out2<<<432, 256, 0, stream>>>(attn_out, wTo, b_out, wTao, b_add_out,
                                     (float*)d_out);
}